// Round 5
// baseline (306.404 us; speedup 1.0000x reference)
//
#include <hip/hip_runtime.h>
#include <stdint.h>

// PWC-Net FunctionCorrelation (81 disp) + LeakyReLU(0.1) via bf16 MFMA.
// out[n, dy*9+dx, y, x] = leaky((1/256) Σ_c f1[n,c,y,x] f2p[n,c,y+dy-4,x+dx-4])
//
// R7 (2nd resubmit -- R3/R4 benches were GPUAcquisitionTimeout, never ran).
// R2 post-mortem: per-chunk wall ~constant across rounds; occupancy was
// REGISTER-limited (64 VGPR + 72 AGPR acc -> 3 waves/SIMD = 35%), and
// aggregate load-return ran at ~5 B/cy/CU, half the ~10 B/cy/CU per-CU
// line-path ceiling (m13). Fix: split the 24-wide j-panel across waves --
// wave = (y-row wy, j-half h), 16 waves, acc[9] (36 regs) instead of
// 8 waves x acc[9][2] (72). Same MFMA total, same LDS layout; one
// 1024-thread block replaces the 2-block pair at 4 waves/SIMD (+33% waves).
// Freed registers fund a DEPTH-2 global prefetch (chunk i+2 issued at chunk
// i). B2 staging remapped to quad-channel on dedicated threads (half the
// line-touches) with b64 LDS writes.
//
// Banded-GEMM per (wy, h, dy): D[16m][16n] = A·B^T, K=256.
//   A[m][k]  = f1[c0+k, y0+wy, x0+m]              (m 0..15, all outputs)
//   B[n][k]  = f2p[c0+k, y0+wy+dy-4, x0-4+8h+n]   (panel j = 8h+n, j 0..23)
//   out(x=x0+m, dx=j-m) valid 0<=dx<=8; h0 owns j<16, h1 owns j>=16.

constexpr int MAXD = 4;
constexpr int N_ = 8, C_ = 256, H_ = 80, W_ = 160, HW_ = H_ * W_;
constexpr int YT = 8, XT = 16;
constexpr int KC = 32;                  // channels per chunk
constexpr int NCH = C_ / KC;            // 8
constexpr int KLINE = 20;               // words/k-line: 16 data + 4 pad (b128 align)
constexpr int AROW  = 16 * KLINE;       // 320 words per A y-row (16 m k-lines)
constexpr int BROW  = 24 * KLINE;       // 480 words per B source row (24 j k-lines)
constexpr int ASZ   = YT * AROW;        // 2560 words
constexpr int BSZ   = 16 * BROW;        // 7680 words
constexpr int BUFW  = ASZ + BSZ;        // 10240 words = 40960 B per buffer
constexpr int NTHR  = 1024;

typedef __attribute__((ext_vector_type(8))) short  frag_ab;   // 8 bf16
typedef __attribute__((ext_vector_type(4))) float  frag_cd;   // 4 fp32

__device__ __forceinline__ uint32_t pkbf(float a, float b) {
    // pack 2 floats -> 2 bf16 (RNE), low half = a (k even)
    uint32_t ua = __float_as_uint(a), ub = __float_as_uint(b);
    ua += 0x7fff + ((ua >> 16) & 1);
    ub += 0x7fff + ((ub >> 16) & 1);
    return (ua >> 16) | (ub & 0xffff0000u);
}

__global__ __launch_bounds__(NTHR, 4)
void corr_mfma_kernel(const float* __restrict__ f1,
                      const float* __restrict__ f2,
                      float* __restrict__ out)
{
    __shared__ uint32_t lds[2 * BUFW];   // 81920 B, 1 block/CU

    const int t    = threadIdx.x;
    const int wid  = t >> 6;             // 0..15
    const int wy   = wid & 7;            // wave's y row
    const int h    = wid >> 3;           // wave's j-half (0: j0..15, 1: j8..23)
    const int lane = t & 63;
    const int nn   = lane & 15;          // MFMA col (n)
    const int qq   = lane >> 4;          // quad (k-group / D row group)

    const int bid = blockIdx.x;
    const int img = bid & 7;             // XCD-pinned image
    const int tr  = bid >> 3;            // 0..99
    const int y0  = (tr / 10) * YT;
    const int x0  = (tr % 10) * XT;      // 0..144, line-aligned
    const int phase = img;

    const float* f1n = f1 + (size_t)img * C_ * HW_;
    const float* f2n = f2 + (size_t)img * C_ * HW_;

    // ---------- staging roles (wave-uniform thread ranges) ----------
    // t <  512 : B1 -- j 0..15. quad-channel: xq(4) x cq(8) x row(16). 4 f4.
    // t in [512,768): B2 -- j 16..23. quad-channel: xh(2) x cq(8) x row(16). 4 f4.
    // t >= 512 : A  -- pair-channel: xq(4) x cp(16) x row(8). 2 f4.
    const bool doB = (t < 768);
    const bool isB1 = (t < 512);
    const bool doA = (t >= 512);

    // B1 map
    const int xq1 = t & 3;
    const int cq1 = (t >> 2) & 7;
    const int s1  = t >> 5;                        // 0..15
    const int ys1 = y0 + s1 - MAXD;
    const bool rok1 = (unsigned)ys1 < (unsigned)H_;
    const int xB1 = x0 - MAXD + 4 * xq1;           // quad fully in or out
    const bool vB1 = rok1 && (xB1 >= 0);           // right edge never OOB here
    const int offB1 = (4 * cq1) * HW_ + (rok1 ? ys1 * W_ : 0) + (vB1 ? xB1 : 0);

    // B2 map
    const int u2  = (t >= 512) ? (t - 512) : 0;
    const int xh2 = u2 & 1;
    const int cq2 = (u2 >> 1) & 7;
    const int s2  = u2 >> 4;                       // 0..15
    const int ys2 = y0 + s2 - MAXD;
    const bool rok2 = (unsigned)ys2 < (unsigned)H_;
    const int xB2 = x0 + 12 + 4 * xh2;             // j 16..23
    const bool vB2 = rok2 && ((xB2 + 3) < W_);     // right edge OOB at x0=144
    const int offB2 = (4 * cq2) * HW_ + (rok2 ? ys2 * W_ : 0) + (vB2 ? xB2 : 0);

    // unified B load predicate / offsets / LDS dest
    const bool vB   = isB1 ? vB1 : vB2;
    const int  offB = isB1 ? offB1 : offB2;
    const int  bwrd = isB1 ? (ASZ + s1 * BROW + (4 * xq1) * KLINE + 2 * cq1)
                           : (ASZ + s2 * BROW + (16 + 4 * xh2) * KLINE + 2 * cq2);

    // A map (no bounds checks: XT=16 divides W, rows valid)
    const int ua  = (t >= 512) ? (t - 512) : 0;
    const int xqA = ua & 3;
    const int cpA = (ua >> 2) & 15;
    const int rA  = ua >> 6;                       // 0..7
    const int offA = (2 * cpA) * HW_ + (y0 + rA) * W_ + (x0 + 4 * xqA);
    const int awrd = rA * AROW + (4 * xqA) * KLINE + cpA;

    // ---------- fragment read offsets (words) ----------
    const int afrag = wy * AROW + nn * KLINE + 4 * qq;
    const int bfrag = ASZ + wy * BROW + (8 * h + nn) * KLINE + 4 * qq; // + d*BROW

    frag_cd acc[9];
#pragma unroll
    for (int d = 0; d < 9; ++d) acc[d] = (frag_cd){0.f, 0.f, 0.f, 0.f};

    float4 rb0[4], rb1[4], ra0[2], ra1[2];   // two prefetch sets (static idx)

#define CH(i) ((((i) + phase) & 7) * KC)

#define LOADS(S, c0)                                                          \
    {                                                                         \
        const int cb = (c0) * HW_;                                            \
        if (doB) {                                                            \
            _Pragma("unroll")                                                 \
            for (int j = 0; j < 4; ++j)                                       \
                rb##S[j] = vB ? *(const float4*)(f2n + cb + offB + j * HW_)   \
                              : float4{0, 0, 0, 0};                           \
        }                                                                     \
        if (doA) {                                                            \
            _Pragma("unroll")                                                 \
            for (int j = 0; j < 2; ++j)                                       \
                ra##S[j] = *(const float4*)(f1n + cb + offA + j * HW_);       \
        }                                                                     \
    }

#define WRITES(buf, S)                                                        \
    {                                                                         \
        uint32_t* wp = lds + (buf) * BUFW;                                    \
        if (doB) {                                                            \
            const float* b0 = (const float*)&rb##S[0];                        \
            const float* b1 = (const float*)&rb##S[1];                        \
            const float* b2 = (const float*)&rb##S[2];                        \
            const float* b3 = (const float*)&rb##S[3];                        \
            _Pragma("unroll")                                                 \
            for (int i = 0; i < 4; ++i) {                                     \
                uint2 w;                                                      \
                w.x = pkbf(b0[i], b1[i]);                                     \
                w.y = pkbf(b2[i], b3[i]);                                     \
                *(uint2*)(wp + bwrd + i * KLINE) = w;                         \
            }                                                                 \
        }                                                                     \
        if (doA) {                                                            \
            const float* a0 = (const float*)&ra##S[0];                        \
            const float* a1 = (const float*)&ra##S[1];                        \
            _Pragma("unroll")                                                 \
            for (int i = 0; i < 4; ++i)                                       \
                wp[awrd + i * KLINE] = pkbf(a0[i], a1[i]);                    \
        }                                                                     \
    }

#define MFMAS(buf)                                                            \
    {                                                                         \
        const uint32_t* rp = lds + (buf) * BUFW;                              \
        const frag_ab af = *(const frag_ab*)(rp + afrag);                     \
        _Pragma("unroll")                                                     \
        for (int d = 0; d < 9; ++d) {                                         \
            const frag_ab bf = *(const frag_ab*)(rp + bfrag + d * BROW);      \
            acc[d] = __builtin_amdgcn_mfma_f32_16x16x32_bf16(af, bf, acc[d],  \
                                                             0, 0, 0);        \
        }                                                                     \
    }

    // prologue: two chunks in flight, first one staged
    LOADS(0, CH(0));
    LOADS(1, CH(1));
    WRITES(0, 0);
    __syncthreads();

    // main loop, unrolled x2 so all prefetch-set indices are static
#pragma unroll 1
    for (int i = 0; i < NCH; i += 2) {
        // even phase: compute buf0 (chunk i); set0 free -> load chunk i+2
        if (i + 2 < NCH) LOADS(0, CH(i + 2));
        MFMAS(0);
        WRITES(1, 1);                    // stage chunk i+1 (loaded 1 iter ago)
        __syncthreads();

        // odd phase: compute buf1 (chunk i+1); set1 free -> load chunk i+3
        if (i + 3 < NCH) LOADS(1, CH(i + 3));
        MFMAS(1);
        if (i + 2 < NCH) WRITES(0, 0);   // stage chunk i+2
        __syncthreads();
    }

    // ---------- epilogue: band extract, scale, leaky, store ----------
    const float inv_c = 1.0f / (float)C_;
    const int y = y0 + wy;
#pragma unroll
    for (int d = 0; d < 9; ++d) {
#pragma unroll
        for (int r = 0; r < 4; ++r) {
            const int m  = 4 * qq + r;        // output x - x0 (0..15, all valid)
            const int j  = nn + 8 * h;        // B panel column
            const int dx = j - m;
            // h0 owns j<16 (all its nn), h1 owns j>=16 (nn>=8)
            if ((h == 0 || nn >= 8) && (unsigned)dx <= 8u) {
                float e = acc[d][r] * inv_c;
                e = e > 0.0f ? e : 0.1f * e;
                const int ch = d * 9 + dx;
                out[((size_t)(img * 81 + ch) * H_ + y) * W_ + (x0 + m)] = e;
            }
        }
    }
}

extern "C" void kernel_launch(void* const* d_in, const int* in_sizes, int n_in,
                              void* d_out, int out_size, void* d_ws, size_t ws_size,
                              hipStream_t stream) {
    const float* f1 = (const float*)d_in[0];
    const float* f2 = (const float*)d_in[1];
    float* out = (float*)d_out;
    const int nblocks = N_ * (H_ / YT) * (W_ / XT);  // 8*10*10 = 800
    corr_mfma_kernel<<<dim3(nblocks), dim3(NTHR), 0, stream>>>(f1, f2, out);
}